// Round 9
// baseline (3679.372 us; speedup 1.0000x reference)
//
#include <hip/hip_runtime.h>
#include <hip/hip_bf16.h>
#include <math.h>

// Performer (FAVOR+) attention forward, fp32. B=4 H=12 N=4096 D=64 M=256. BH=48.
//
// R6 post-mortem: R1's launch_bounds did nothing (VGPR stuck at 80; acc[64]
// lived in AGPRs, no memory spills — WRITE_SIZE is ~32B/atomicAdd, memory-side
// fp32 atomics). Kernel was latency-bound: 2 waves/SIMD, ~450cy dep chain per
// row vs 256cy issue -> VALUBusy 11%.
//
// R6 design: 4-lane split per feature m (seg = j-quarter = d-quarter):
// pj[16]+acc[16] ~= 48 VGPRs -> no AGPRs, 24 waves/CU. Partial dots combined
// via shfl_xor(1),shfl_xor(2). qout: 512-thr blocks, 32 rows, half-split dots
// (pj[32]), qd straight to LDS, phase-6 reads ctx via broadcast-coalesced L2.
// R7/R8: resubmit unchanged (broker timeouts; R6 design never measured).
//
// ratio = M^-0.5 cancels between numerator/denominator -> omitted.

#define BH 48
#define NSEQ 4096
#define DD 64
#define MM 256
#define EPSF 1e-4f

__device__ __forceinline__ float waveMax(float v) {
    v = fmaxf(v, __shfl_xor(v, 32));
    v = fmaxf(v, __shfl_xor(v, 16));
    v = fmaxf(v, __shfl_xor(v, 8));
    v = fmaxf(v, __shfl_xor(v, 4));
    v = fmaxf(v, __shfl_xor(v, 2));
    v = fmaxf(v, __shfl_xor(v, 1));
    return v;
}

// ---------------- Kernel A: global max of k_dash ----------------
// grid = BH*4*8 = 1536 blocks, 256 thr. Thread: m = mq*64+(t>>2), seg=t&3.
// pj[16] = proj[m][seg*16..+16). Partial dot + shfl_xor(1,2) -> full dot.
__global__ __launch_bounds__(256) void kmax_kernel(
    const float* __restrict__ K, const float* __restrict__ mask,
    const float* __restrict__ proj, float* __restrict__ apart) {
    const int t = threadIdx.x;
    const int bid = blockIdx.x;
    const int bh = bid >> 5;
    const int mq = (bid >> 3) & 3;
    const int chunk = bid & 7;
    const int b = bh / 12;
    const int m = mq * 64 + (t >> 2);
    const int seg = t & 3;
    const int row0 = chunk * 512;
    const float* __restrict__ Kb = K + (size_t)bh * NSEQ * DD;
    const float* __restrict__ mk = mask + (size_t)b * NSEQ;

    float pj[16];
    {
        const float4* pr = (const float4*)(proj + m * DD + seg * 16);
        #pragma unroll
        for (int i = 0; i < 4; ++i) {
            float4 v = pr[i];
            pj[4*i] = v.x; pj[4*i+1] = v.y; pj[4*i+2] = v.z; pj[4*i+3] = v.w;
        }
    }
    float mx = -INFINITY;
    for (int r0 = 0; r0 < 512; ++r0) {
        const int r = row0 + r0;
        const float4* __restrict__ kr = (const float4*)(Kb + (size_t)r * DD + seg * 16);
        float d0 = 0.f, d1 = 0.f, d2 = 0.f, d3 = 0.f;
        #pragma unroll
        for (int j = 0; j < 4; ++j) {
            float4 kv = kr[j];
            d0 = fmaf(kv.x, pj[4*j+0], d0);
            d1 = fmaf(kv.y, pj[4*j+1], d1);
            d2 = fmaf(kv.z, pj[4*j+2], d2);
            d3 = fmaf(kv.w, pj[4*j+3], d3);
        }
        float d = (d0 + d1) + (d2 + d3);
        d += __shfl_xor(d, 1);
        d += __shfl_xor(d, 2);           // full 64-elem dot on all 4 lanes
        mx = fmaxf(mx, d * (mk[r] * 0.125f));
    }
    mx = waveMax(mx);
    __shared__ float wmax[4];
    if ((t & 63) == 0) wmax[t >> 6] = mx;
    __syncthreads();
    if (t == 0)
        apart[bid] = fmaxf(fmaxf(wmax[0], wmax[1]), fmaxf(wmax[2], wmax[3]));
}

__global__ __launch_bounds__(256) void kmax_reduce(
    const float* __restrict__ apart, float* __restrict__ mxout) {
    float v = -INFINITY;
    for (int i = threadIdx.x; i < BH * 32; i += 256) v = fmaxf(v, apart[i]);
    v = waveMax(v);
    __shared__ float w[4];
    if ((threadIdx.x & 63) == 0) w[threadIdx.x >> 6] = v;
    __syncthreads();
    if (threadIdx.x == 0)
        mxout[0] = fmaxf(fmaxf(w[0], w[1]), fmaxf(w[2], w[3]));
}

// ---------------- Kernel B: ctx and ksum ----------------
// grid = BH*4*8 = 1536 blocks (mq m-quarter, chunk of 512 rows), 256 thr.
// Thread: m = mq*64+(t>>2), seg = t&3 (j-quarter AND d-quarter).
// pj[16] + acc[16] -> ~48 VGPRs, no AGPR accumulators.
__global__ __launch_bounds__(256) void kctx_kernel(
    const float* __restrict__ K, const float* __restrict__ V,
    const float* __restrict__ mask, const float* __restrict__ proj,
    const float* __restrict__ wsmx, float* __restrict__ ctx,
    float* __restrict__ ksum) {
    const int t = threadIdx.x;
    const int bid = blockIdx.x;
    const int bh = bid >> 5;
    const int mq = (bid >> 3) & 3;
    const int chunk = bid & 7;
    const int b = bh / 12;
    const int m = mq * 64 + (t >> 2);
    const int seg = t & 3;
    const float MX = wsmx[0];
    const float* __restrict__ Kb = K + (size_t)bh * NSEQ * DD;
    const float* __restrict__ Vb = V + (size_t)bh * NSEQ * DD;
    const float* __restrict__ mk = mask + (size_t)b * NSEQ;

    float pj[16];
    {
        const float4* pr = (const float4*)(proj + m * DD + seg * 16);
        #pragma unroll
        for (int i = 0; i < 4; ++i) {
            float4 v = pr[i];
            pj[4*i] = v.x; pj[4*i+1] = v.y; pj[4*i+2] = v.z; pj[4*i+3] = v.w;
        }
    }
    float acc[16];
    #pragma unroll
    for (int j = 0; j < 16; ++j) acc[j] = 0.f;
    float ks = 0.f;

    __shared__ float lds_a[64], lds_c[64], lds_vm[64];

    for (int sub = 0; sub < 8; ++sub) {
        const int r0 = chunk * 512 + sub * 64;
        // cooperative sum-of-squares for 64 rows (4 threads/row, 16 elems each)
        {
            int rr = t >> 2, sg = t & 3;
            const float4* kq = (const float4*)(Kb + (size_t)(r0 + rr) * DD + sg * 16);
            float s = 0.f;
            #pragma unroll
            for (int i = 0; i < 4; ++i) {
                float4 v = kq[i];
                s += v.x*v.x + v.y*v.y + v.z*v.z + v.w*v.w;
            }
            s += __shfl_xor(s, 1);
            s += __shfl_xor(s, 2);
            if (sg == 0) {
                float mv = mk[r0 + rr];
                lds_a[rr] = mv * 0.125f;
                lds_vm[rr] = mv;
                lds_c[rr] = -(mv * mv) * (s * (1.f / 128.f)) - MX;
            }
        }
        __syncthreads();
        for (int r = 0; r < 64; ++r) {
            const float4* __restrict__ kr = (const float4*)(Kb + (size_t)(r0 + r) * DD + seg * 16);
            float a = lds_a[r], c = lds_c[r], vm = lds_vm[r];   // LDS broadcast
            float d0 = 0.f, d1 = 0.f, d2 = 0.f, d3 = 0.f;
            #pragma unroll
            for (int j = 0; j < 4; ++j) {
                float4 kv = kr[j];
                d0 = fmaf(kv.x, pj[4*j+0], d0);
                d1 = fmaf(kv.y, pj[4*j+1], d1);
                d2 = fmaf(kv.z, pj[4*j+2], d2);
                d3 = fmaf(kv.w, pj[4*j+3], d3);
            }
            float d = (d0 + d1) + (d2 + d3);
            d += __shfl_xor(d, 1);
            d += __shfl_xor(d, 2);       // full dot on all 4 lanes of the quad
            float e = __expf(fmaf(d, a, c)) + EPSF;
            ks += e;                      // only seg==0 commits at the end
            float kpv = e * vm;
            const float4* __restrict__ vr = (const float4*)(Vb + (size_t)(r0 + r) * DD + seg * 16);
            #pragma unroll
            for (int j = 0; j < 4; ++j) {
                float4 vv = vr[j];
                acc[4*j+0] = fmaf(vv.x, kpv, acc[4*j+0]);
                acc[4*j+1] = fmaf(vv.y, kpv, acc[4*j+1]);
                acc[4*j+2] = fmaf(vv.z, kpv, acc[4*j+2]);
                acc[4*j+3] = fmaf(vv.w, kpv, acc[4*j+3]);
            }
        }
        __syncthreads();
    }
    float* cdst = ctx + ((size_t)bh * MM + m) * DD + seg * 16;
    #pragma unroll
    for (int j = 0; j < 16; ++j) atomicAdd(cdst + j, acc[j]);
    if (seg == 0) atomicAdd(ksum + (size_t)bh * MM + m, ks);
}

// ---------------- Kernel C: fused q' -> out ----------------
// grid = BH*128 blocks, 512 threads, 32 rows/block. qp[256][34] (34.8KB LDS).
__global__ __launch_bounds__(512) void qout_kernel(
    const float* __restrict__ Q, const float* __restrict__ proj,
    const float* __restrict__ ctx, const float* __restrict__ ksum,
    float* __restrict__ out) {
    const int t = threadIdx.x;
    const int bh = blockIdx.x >> 7;
    const int tile = blockIdx.x & 127;
    const int row0 = tile * 32;
    const float* __restrict__ Qb = Q + (size_t)bh * NSEQ * DD;

    __shared__ float qp[256][34];
    __shared__ float ssq[32], mxs[32], dnv[32];

    // phase 0: sum of squares per row (16 threads/row, 4 elems each)
    {
        int rr = t >> 4, sg = t & 15;
        const float4* qq = (const float4*)(Qb + (size_t)(row0 + rr) * DD + sg * 4);
        float4 v = qq[0];
        float s = v.x*v.x + v.y*v.y + v.z*v.z + v.w*v.w;
        s += __shfl_xor(s, 1);
        s += __shfl_xor(s, 2);
        s += __shfl_xor(s, 4);
        s += __shfl_xor(s, 8);
        if (sg == 0) ssq[rr] = s;
    }
    // phase 1: thread pair per m (m = t>>1, h = t&1), pj[32] = proj[m][h*32..]
    {
        const int m = t >> 1, h = t & 1;
        float pj[32];
        const float4* pr = (const float4*)(proj + m * DD + h * 32);
        #pragma unroll
        for (int i = 0; i < 8; ++i) {
            float4 v = pr[i];
            pj[4*i] = v.x; pj[4*i+1] = v.y; pj[4*i+2] = v.z; pj[4*i+3] = v.w;
        }
        for (int r = 0; r < 32; ++r) {
            const float4* __restrict__ qr = (const float4*)(Qb + (size_t)(row0 + r) * DD + h * 32);
            float d0 = 0.f, d1 = 0.f, d2 = 0.f, d3 = 0.f;
            #pragma unroll
            for (int j = 0; j < 8; ++j) {
                float4 qv = qr[j];
                d0 = fmaf(qv.x, pj[4*j+0], d0);
                d1 = fmaf(qv.y, pj[4*j+1], d1);
                d2 = fmaf(qv.z, pj[4*j+2], d2);
                d3 = fmaf(qv.w, pj[4*j+3], d3);
            }
            float d = (d0 + d1) + (d2 + d3);
            d += __shfl_xor(d, 1);       // combine halves within the pair
            if (h == 0) qp[m][r] = d * 0.125f;
        }
    }
    __syncthreads();
    // phase 3: row max over 256 m (16 threads/row, 16 m each)
    {
        int r = t >> 4, j = t & 15;
        float mx = -INFINITY;
        #pragma unroll
        for (int i = 0; i < 16; ++i) mx = fmaxf(mx, qp[j * 16 + i][r]);
        mx = fmaxf(mx, __shfl_xor(mx, 1));
        mx = fmaxf(mx, __shfl_xor(mx, 2));
        mx = fmaxf(mx, __shfl_xor(mx, 4));
        mx = fmaxf(mx, __shfl_xor(mx, 8));
        if (j == 0) mxs[r] = mx;
    }
    __syncthreads();
    // phase 4: q' = exp(qd - ssq/128 - mx) + eps (m = t>>1, 16 rows per half)
    {
        int m = t >> 1, h = t & 1;
        #pragma unroll
        for (int rr = 0; rr < 16; ++rr) {
            int r = h * 16 + rr;
            float arg = qp[m][r] - ssq[r] * (1.f / 128.f) - mxs[r];
            qp[m][r] = __expf(arg) + EPSF;
        }
    }
    __syncthreads();
    // phase 5: denom (16 threads/row, 16 m each)
    {
        int r = t >> 4, j = t & 15;
        const float* __restrict__ ksb = ksum + (size_t)bh * MM;
        float s = 0.f;
        #pragma unroll
        for (int i = 0; i < 16; ++i) {
            int m2 = j * 16 + i;
            s = fmaf(qp[m2][r], ksb[m2], s);
        }
        s += __shfl_xor(s, 1);
        s += __shfl_xor(s, 2);
        s += __shfl_xor(s, 4);
        s += __shfl_xor(s, 8);
        if (j == 0) dnv[r] = 1.f / s;
    }
    __syncthreads();
    // phase 6: out[r][c..c+3] = (sum_m qp[m][r]*ctx[m][c..]) * dinv[r]
    {
        int r = t >> 4, c = (t & 15) * 4;   // 32 rows x 16 col-groups
        const float4* cb = (const float4*)(ctx + (size_t)bh * MM * DD + c);
        float4 acc = {0.f, 0.f, 0.f, 0.f};
        #pragma unroll 4
        for (int m2 = 0; m2 < 256; ++m2) {
            float q = qp[m2][r];
            float4 cv = cb[(size_t)m2 * 16];
            acc.x = fmaf(q, cv.x, acc.x);
            acc.y = fmaf(q, cv.y, acc.y);
            acc.z = fmaf(q, cv.z, acc.z);
            acc.w = fmaf(q, cv.w, acc.w);
        }
        float di = dnv[r];
        acc.x *= di; acc.y *= di; acc.z *= di; acc.w *= di;
        *(float4*)(out + ((size_t)bh * NSEQ + row0 + r) * DD + c) = acc;
    }
}

extern "C" void kernel_launch(void* const* d_in, const int* in_sizes, int n_in,
                              void* d_out, int out_size, void* d_ws, size_t ws_size,
                              hipStream_t stream) {
    const float* Q    = (const float*)d_in[0];
    const float* K    = (const float*)d_in[1];
    const float* V    = (const float*)d_in[2];
    const float* mask = (const float*)d_in[3];
    const float* proj = (const float*)d_in[4];
    float* out = (float*)d_out;
    float* ws  = (float*)d_ws;

    float* mx    = ws;            // [0]
    float* apart = ws + 64;       // 1536 block maxima
    float* ksum  = ws + 2048;     // BH*256
    float* ctx   = ws + 16384;    // BH*256*64 (ends at 802816 floats = 3.2 MB)

    // zero the atomically-accumulated region (ksum..ctx end)
    hipMemsetAsync(ksum, 0, (size_t)(802816 - 2048) * sizeof(float), stream);

    kmax_kernel<<<BH * 32, 256, 0, stream>>>(K, mask, proj, apart);
    kmax_reduce<<<1, 256, 0, stream>>>(apart, mx);
    kctx_kernel<<<BH * 32, 256, 0, stream>>>(K, V, mask, proj, mx, ctx, ksum);
    qout_kernel<<<BH * 128, 512, 0, stream>>>(Q, proj, ctx, ksum, out);
}

// Round 11
// 474.107 us; speedup vs baseline: 7.7606x; 7.7606x over previous
//
#include <hip/hip_runtime.h>
#include <hip/hip_bf16.h>
#include <math.h>

// Performer (FAVOR+) attention forward. B=4 H=12 N=4096 D=64 M=256. BH=48.
//
// R9: MFMA rewrite. R1/R6 post-mortems: two different fp32-VALU designs both
// pinned at VALUBusy ~12% regardless of occupancy (26% vs 68%) — per-row
// broadcast-load + cross-lane serial chains stall ~88% independent of wave
// count. The op is three GEMMs; move them to matrix cores.
// R10: resubmit unchanged (broker timeout; R9 never measured). Source re-audited:
// frag mappings, ksum shuffle, denom aug-row, sync ordering, LDS/ws budgets OK.
//
// Math: kd = Khat·P^T (Khat = K·mask/8), diag_k = 0.5·sum(Khat^2),
// E = exp(kd - diag - MX) + eps; ctx = E^T·(V·mask), ksum = sum_rows E;
// qd = Qhat·P^T (Qhat = Q/8), q' = exp(qd - diag_q - rowmax) + eps;
// out = (q'·ctx)/(q'·ksum). ratio = M^-0.5 cancels.
//
// Precision: split-bf16 3-pass (a=hi+lo; hi·hi + hi·lo + lo·hi MFMA passes,
// fp32 accum; dropped lo·lo ~ 2^-18 rel) everywhere.
//
// MFMA 16x16x32 bf16 layouts (guide-verified D; ladder-consistent A/B):
//   A frag: lane reads Arow[l&15], k = 8*(l>>4)+j  (b128 of 8 bf16)
//   B frag: lane reads Bt-row[l&15] (=N idx), k = 8*(l>>4)+j  (B stored [N][K])
//   D frag: col = l&15 (N), row = (l>>4)*4 + reg (M)

#define BH 48
#define NSEQ 4096
#define DD 64
#define MM 256
#define EPSF 1e-4f

typedef unsigned short ushort_t;
typedef __attribute__((ext_vector_type(8))) short short8v;
typedef __attribute__((ext_vector_type(4))) float f32x4;

#define MFMA16(a, b, c) __builtin_amdgcn_mfma_f32_16x16x32_bf16((a), (b), (c), 0, 0, 0)

__device__ __forceinline__ ushort_t f2bf(float x) {
    unsigned int u = __float_as_uint(x);
    unsigned int r = (u + 0x7FFFu + ((u >> 16) & 1u)) >> 16;
    return (ushort_t)r;
}
__device__ __forceinline__ float bf2f(ushort_t h) {
    return __uint_as_float(((unsigned int)h) << 16);
}

__device__ __forceinline__ float waveMax(float v) {
    v = fmaxf(v, __shfl_xor(v, 32));
    v = fmaxf(v, __shfl_xor(v, 16));
    v = fmaxf(v, __shfl_xor(v, 8));
    v = fmaxf(v, __shfl_xor(v, 4));
    v = fmaxf(v, __shfl_xor(v, 2));
    v = fmaxf(v, __shfl_xor(v, 1));
    return v;
}

// ---------------- prep: proj fp32 -> bf16 hi/lo ----------------
__global__ __launch_bounds__(256) void prep_kernel(
    const float* __restrict__ proj, ushort_t* __restrict__ Phi,
    ushort_t* __restrict__ Plo) {
    int i = blockIdx.x * 256 + threadIdx.x;   // 64 blocks -> 16384 elems
    float x = proj[i];
    ushort_t h = f2bf(x);
    Phi[i] = h;
    Plo[i] = f2bf(x - bf2f(h));
}

// ---------------- kmax: global max of kd via split-MFMA ----------------
// grid 48*16 = 768 blocks, 256 thr. Wave w does rowblocks w*4..w*4+3 (16 rows each).
__global__ __launch_bounds__(256) void kmax_mfma(
    const float* __restrict__ K, const float* __restrict__ mask,
    const ushort_t* __restrict__ Phi, const ushort_t* __restrict__ Plo,
    float* __restrict__ apart) {
    const int t = threadIdx.x;
    const int bh = blockIdx.x >> 4;
    const int chunk = blockIdx.x & 15;
    const int b = bh / 12;
    const int wv = t >> 6, lane = t & 63, lq = lane >> 4, lr = lane & 15;
    const float* __restrict__ Kb = K + (size_t)bh * NSEQ * DD;
    const float* __restrict__ mk = mask + (size_t)b * NSEQ;

    __shared__ ushort_t khi[4][16][72], klo[4][16][72];

    float mx = -INFINITY;
    for (int rb = 0; rb < 4; ++rb) {
        const int r0 = chunk * 256 + (wv * 4 + rb) * 16;
        // stage Khat = K*mask/8 as bf16 hi/lo (lane: row=lane>>2, 16 floats)
        {
            int srow = lane >> 2, sseg = lane & 3;
            const float4* kg = (const float4*)(Kb + (size_t)(r0 + srow) * DD + sseg * 16);
            float a = mk[r0 + srow] * 0.125f;
            #pragma unroll
            for (int i = 0; i < 4; ++i) {
                float4 v = kg[i];
                float xs[4] = {v.x * a, v.y * a, v.z * a, v.w * a};
                #pragma unroll
                for (int c = 0; c < 4; ++c) {
                    ushort_t h = f2bf(xs[c]);
                    khi[wv][srow][sseg * 16 + i * 4 + c] = h;
                    klo[wv][srow][sseg * 16 + i * 4 + c] = f2bf(xs[c] - bf2f(h));
                }
            }
        }
        __syncthreads();
        short8v ahi[2], alo[2];
        #pragma unroll
        for (int h = 0; h < 2; ++h) {
            ahi[h] = *(const short8v*)&khi[wv][lr][h * 32 + 8 * lq];
            alo[h] = *(const short8v*)&klo[wv][lr][h * 32 + 8 * lq];
        }
        for (int nt = 0; nt < 16; ++nt) {
            f32x4 Dv = {0.f, 0.f, 0.f, 0.f};
            #pragma unroll
            for (int h = 0; h < 2; ++h) {
                int po = (nt * 16 + lr) * DD + h * 32 + 8 * lq;
                short8v bh8 = *(const short8v*)(Phi + po);
                short8v bl8 = *(const short8v*)(Plo + po);
                Dv = MFMA16(ahi[h], bh8, Dv);
                Dv = MFMA16(ahi[h], bl8, Dv);
                Dv = MFMA16(alo[h], bh8, Dv);
            }
            mx = fmaxf(mx, fmaxf(fmaxf(Dv[0], Dv[1]), fmaxf(Dv[2], Dv[3])));
        }
        __syncthreads();
    }
    mx = waveMax(mx);
    __shared__ float wm[4];
    if (lane == 0) wm[wv] = mx;
    __syncthreads();
    if (t == 0)
        apart[blockIdx.x] = fmaxf(fmaxf(wm[0], wm[1]), fmaxf(wm[2], wm[3]));
}

__global__ __launch_bounds__(256) void kmax_reduce(
    const float* __restrict__ apart, float* __restrict__ mxout) {
    float v = -INFINITY;
    for (int i = threadIdx.x; i < BH * 16; i += 256) v = fmaxf(v, apart[i]);
    v = waveMax(v);
    __shared__ float w[4];
    if ((threadIdx.x & 63) == 0) w[threadIdx.x >> 6] = v;
    __syncthreads();
    if (threadIdx.x == 0)
        mxout[0] = fmaxf(fmaxf(w[0], w[1]), fmaxf(w[2], w[3]));
}

// ---------------- kctx: E (GEMM1+exp) fused with ctx=E^T V' (GEMM2) ----------
// grid 48*16 = 768 blocks, 256 thr, 4 waves. 256 rows/block, 8 batches of 32.
// Wave wv owns m-range wv*64..wv*64+63.
__global__ __launch_bounds__(256) void kctx_mfma(
    const float* __restrict__ K, const float* __restrict__ V,
    const float* __restrict__ mask, const ushort_t* __restrict__ Phi,
    const ushort_t* __restrict__ Plo, const float* __restrict__ wsmx,
    float* __restrict__ ctx, float* __restrict__ ksum) {
    const int t = threadIdx.x;
    const int bh = blockIdx.x >> 4;
    const int chunk = blockIdx.x & 15;
    const int b = bh / 12;
    const int wv = t >> 6, lane = t & 63, lq = lane >> 4, lr = lane & 15;
    const float MX = wsmx[0];
    const float* __restrict__ Kb = K + (size_t)bh * NSEQ * DD;
    const float* __restrict__ Vb = V + (size_t)bh * NSEQ * DD;
    const float* __restrict__ mk = mask + (size_t)b * NSEQ;

    __shared__ ushort_t khi[32][72], klo[32][72];     //  9216 B
    __shared__ ushort_t vthi[64][40], vtlo[64][40];   // 10240 B (Vt[d][row])
    __shared__ ushort_t ehi[256][40], elo[256][40];   // 40960 B (E[m][row])
    __shared__ float ck[32];

    f32x4 ctxD[4][4];
    #pragma unroll
    for (int i = 0; i < 4; ++i)
        #pragma unroll
        for (int j = 0; j < 4; ++j) ctxD[i][j] = (f32x4){0.f, 0.f, 0.f, 0.f};
    float ksacc[4] = {0.f, 0.f, 0.f, 0.f};

    const int srow = t >> 3, sseg = t & 7;  // staging: 8 threads/row, 8 floats each

    for (int batch = 0; batch < 8; ++batch) {
        const int r0 = chunk * 256 + batch * 32;
        // ---- stage Khat (and ck = -0.5*ssq - MX), Vt = (V*mask)^T ----
        {
            const float4* kg = (const float4*)(Kb + (size_t)(r0 + srow) * DD + sseg * 8);
            float a = mk[r0 + srow] * 0.125f;
            float4 v0 = kg[0], v1 = kg[1];
            float xs[8] = {v0.x * a, v0.y * a, v0.z * a, v0.w * a,
                           v1.x * a, v1.y * a, v1.z * a, v1.w * a};
            float ss = 0.f;
            #pragma unroll
            for (int i = 0; i < 8; ++i) ss += xs[i] * xs[i];
            ss += __shfl_xor(ss, 1);
            ss += __shfl_xor(ss, 2);
            ss += __shfl_xor(ss, 4);
            if (sseg == 0) ck[srow] = -0.5f * ss - MX;
            #pragma unroll
            for (int i = 0; i < 8; ++i) {
                ushort_t h = f2bf(xs[i]);
                khi[srow][sseg * 8 + i] = h;
                klo[srow][sseg * 8 + i] = f2bf(xs[i] - bf2f(h));
            }
            const float4* vg = (const float4*)(Vb + (size_t)(r0 + srow) * DD + sseg * 8);
            float vm = mk[r0 + srow];
            float4 w0 = vg[0], w1 = vg[1];
            float vs[8] = {w0.x * vm, w0.y * vm, w0.z * vm, w0.w * vm,
                           w1.x * vm, w1.y * vm, w1.z * vm, w1.w * vm};
            #pragma unroll
            for (int i = 0; i < 8; ++i) {
                ushort_t h = f2bf(vs[i]);
                vthi[sseg * 8 + i][srow] = h;
                vtlo[sseg * 8 + i][srow] = f2bf(vs[i] - bf2f(h));
            }
        }
        __syncthreads();
        // ---- GEMM1 (kd) + exp epilogue -> E in LDS (transposed) ----
        {
            short8v ahi[2][2], alo[2][2];
            #pragma unroll
            for (int Mt = 0; Mt < 2; ++Mt)
                #pragma unroll
                for (int h = 0; h < 2; ++h) {
                    ahi[Mt][h] = *(const short8v*)&khi[Mt * 16 + lr][h * 32 + 8 * lq];
                    alo[Mt][h] = *(const short8v*)&klo[Mt * 16 + lr][h * 32 + 8 * lq];
                }
            for (int nt = 0; nt < 4; ++nt) {
                const int m0 = wv * 64 + nt * 16;
                short8v bh8[2], bl8[2];
                #pragma unroll
                for (int h = 0; h < 2; ++h) {
                    int po = (m0 + lr) * DD + h * 32 + 8 * lq;
                    bh8[h] = *(const short8v*)(Phi + po);
                    bl8[h] = *(const short8v*)(Plo + po);
                }
                #pragma unroll
                for (int Mt = 0; Mt < 2; ++Mt) {
                    f32x4 Dv = {0.f, 0.f, 0.f, 0.f};
                    #pragma unroll
                    for (int h = 0; h < 2; ++h) {
                        Dv = MFMA16(ahi[Mt][h], bh8[h], Dv);
                        Dv = MFMA16(ahi[Mt][h], bl8[h], Dv);
                        Dv = MFMA16(alo[Mt][h], bh8[h], Dv);
                    }
                    float spart = 0.f;
                    #pragma unroll
                    for (int reg = 0; reg < 4; ++reg) {
                        int row = Mt * 16 + lq * 4 + reg;
                        float e = __expf(Dv[reg] + ck[row]) + EPSF;
                        spart += e;
                        ushort_t h16 = f2bf(e);
                        ehi[m0 + lr][row] = h16;
                        elo[m0 + lr][row] = f2bf(e - bf2f(h16));
                    }
                    spart += __shfl_xor(spart, 16);
                    spart += __shfl_xor(spart, 32);
                    ksacc[nt] += spart;
                }
            }
        }
        __syncthreads();
        // ---- GEMM2 partial: ctx += E^T · Vt (K = 32 rows of this batch) ----
        {
            short8v b2h[4], b2l[4];
            #pragma unroll
            for (int nt2 = 0; nt2 < 4; ++nt2) {
                b2h[nt2] = *(const short8v*)&vthi[nt2 * 16 + lr][8 * lq];
                b2l[nt2] = *(const short8v*)&vtlo[nt2 * 16 + lr][8 * lq];
            }
            #pragma unroll
            for (int Mt2 = 0; Mt2 < 4; ++Mt2) {
                const int m0 = wv * 64 + Mt2 * 16;
                short8v a2h = *(const short8v*)&ehi[m0 + lr][8 * lq];
                short8v a2l = *(const short8v*)&elo[m0 + lr][8 * lq];
                #pragma unroll
                for (int nt2 = 0; nt2 < 4; ++nt2) {
                    f32x4 acc = ctxD[Mt2][nt2];
                    acc = MFMA16(a2h, b2h[nt2], acc);
                    acc = MFMA16(a2h, b2l[nt2], acc);
                    acc = MFMA16(a2l, b2h[nt2], acc);
                    ctxD[Mt2][nt2] = acc;
                }
            }
        }
        __syncthreads();
    }
    // ---- commit ----
    #pragma unroll
    for (int Mt2 = 0; Mt2 < 4; ++Mt2)
        #pragma unroll
        for (int nt2 = 0; nt2 < 4; ++nt2)
            #pragma unroll
            for (int reg = 0; reg < 4; ++reg) {
                int m = wv * 64 + Mt2 * 16 + lq * 4 + reg;
                int d = nt2 * 16 + lr;
                atomicAdd(&ctx[((size_t)bh * MM + m) * DD + d], ctxD[Mt2][nt2][reg]);
            }
    if (lq == 0) {
        #pragma unroll
        for (int nt = 0; nt < 4; ++nt)
            atomicAdd(&ksum[(size_t)bh * MM + wv * 64 + nt * 16 + lr], ksacc[nt]);
    }
}

// ---------------- ctxcvt: ctx fp32 + ksum -> Ct bf16 hi/lo [bh][80][256] ------
__global__ __launch_bounds__(256) void ctxcvt_kernel(
    const float* __restrict__ ctx, const float* __restrict__ ksum,
    ushort_t* __restrict__ Cthi, ushort_t* __restrict__ Ctlo) {
    const int bh = blockIdx.x;
    for (int i = threadIdx.x; i < 80 * 256; i += 256) {
        int d = i >> 8, m = i & 255;
        float v = 0.f;
        if (d < 64) v = ctx[((size_t)bh * MM + m) * DD + d];
        else if (d == 64) v = ksum[(size_t)bh * MM + m];
        ushort_t h = f2bf(v);
        Cthi[(size_t)bh * 80 * 256 + i] = h;
        Ctlo[(size_t)bh * 80 * 256 + i] = f2bf(v - bf2f(h));
    }
}

// ---------------- qout: qd GEMM + softmax-kernel + out = (q'·C)/denom --------
// grid 48*128 = 6144 blocks, 256 thr, 4 waves, 32 rows/block.
// GEMM1q: wave wv owns m-range wv*64. GEMM3: wave wv owns d-tile wv (wave0 also denom tile).
__global__ __launch_bounds__(256) void qout_mfma(
    const float* __restrict__ Q, const ushort_t* __restrict__ Phi,
    const ushort_t* __restrict__ Plo, const ushort_t* __restrict__ Cthi,
    const ushort_t* __restrict__ Ctlo, float* __restrict__ out) {
    const int t = threadIdx.x;
    const int bh = blockIdx.x >> 7;
    const int tile = blockIdx.x & 127;
    const int r0 = tile * 32;
    const int wv = t >> 6, lane = t & 63, lq = lane >> 4, lr = lane & 15;
    const float* __restrict__ Qb = Q + (size_t)bh * NSEQ * DD;

    __shared__ ushort_t qhi[32][72], qlo[32][72];       //  9216 B
    __shared__ ushort_t qphi[32][264], qplo[32][264];   // 33792 B
    __shared__ float cq[32], pmax[4][32], dnv[32];

    // ---- stage Qhat = Q/8, cq = -0.5*ssq ----
    {
        int srow = t >> 3, sseg = t & 7;
        const float4* qg = (const float4*)(Qb + (size_t)(r0 + srow) * DD + sseg * 8);
        float4 v0 = qg[0], v1 = qg[1];
        float xs[8] = {v0.x * 0.125f, v0.y * 0.125f, v0.z * 0.125f, v0.w * 0.125f,
                       v1.x * 0.125f, v1.y * 0.125f, v1.z * 0.125f, v1.w * 0.125f};
        float ss = 0.f;
        #pragma unroll
        for (int i = 0; i < 8; ++i) ss += xs[i] * xs[i];
        ss += __shfl_xor(ss, 1);
        ss += __shfl_xor(ss, 2);
        ss += __shfl_xor(ss, 4);
        if (sseg == 0) cq[srow] = -0.5f * ss;
        #pragma unroll
        for (int i = 0; i < 8; ++i) {
            ushort_t h = f2bf(xs[i]);
            qhi[srow][sseg * 8 + i] = h;
            qlo[srow][sseg * 8 + i] = f2bf(xs[i] - bf2f(h));
        }
    }
    __syncthreads();
    // ---- GEMM1q: qd for wave's 64 m ----
    f32x4 Dq[2][4];
    {
        short8v ahi[2][2], alo[2][2];
        #pragma unroll
        for (int Mt = 0; Mt < 2; ++Mt)
            #pragma unroll
            for (int h = 0; h < 2; ++h) {
                ahi[Mt][h] = *(const short8v*)&qhi[Mt * 16 + lr][h * 32 + 8 * lq];
                alo[Mt][h] = *(const short8v*)&qlo[Mt * 16 + lr][h * 32 + 8 * lq];
            }
        for (int nt = 0; nt < 4; ++nt) {
            const int m0 = wv * 64 + nt * 16;
            short8v bh8[2], bl8[2];
            #pragma unroll
            for (int h = 0; h < 2; ++h) {
                int po = (m0 + lr) * DD + h * 32 + 8 * lq;
                bh8[h] = *(const short8v*)(Phi + po);
                bl8[h] = *(const short8v*)(Plo + po);
            }
            #pragma unroll
            for (int Mt = 0; Mt < 2; ++Mt) {
                f32x4 Dv = {0.f, 0.f, 0.f, 0.f};
                #pragma unroll
                for (int h = 0; h < 2; ++h) {
                    Dv = MFMA16(ahi[Mt][h], bh8[h], Dv);
                    Dv = MFMA16(ahi[Mt][h], bl8[h], Dv);
                    Dv = MFMA16(alo[Mt][h], bh8[h], Dv);
                }
                Dq[Mt][nt] = Dv;
            }
        }
    }
    // wave-partial rowmax over its 64 m
    #pragma unroll
    for (int Mt = 0; Mt < 2; ++Mt)
        #pragma unroll
        for (int reg = 0; reg < 4; ++reg) {
            float mm = fmaxf(fmaxf(Dq[Mt][0][reg], Dq[Mt][1][reg]),
                             fmaxf(Dq[Mt][2][reg], Dq[Mt][3][reg]));
            mm = fmaxf(mm, __shfl_xor(mm, 1));
            mm = fmaxf(mm, __shfl_xor(mm, 2));
            mm = fmaxf(mm, __shfl_xor(mm, 4));
            mm = fmaxf(mm, __shfl_xor(mm, 8));
            if (lr == 0) pmax[wv][Mt * 16 + lq * 4 + reg] = mm;
        }
    __syncthreads();
    // ---- q' epilogue -> qp LDS [row][m] bf16 hi/lo ----
    #pragma unroll
    for (int Mt = 0; Mt < 2; ++Mt)
        #pragma unroll
        for (int reg = 0; reg < 4; ++reg) {
            int row = Mt * 16 + lq * 4 + reg;
            float rmx = fmaxf(fmaxf(pmax[0][row], pmax[1][row]),
                              fmaxf(pmax[2][row], pmax[3][row]));
            float base = cq[row] - rmx;
            #pragma unroll
            for (int nt = 0; nt < 4; ++nt) {
                int m = wv * 64 + nt * 16 + lr;
                float e = __expf(Dq[Mt][nt][reg] + base) + EPSF;
                ushort_t h16 = f2bf(e);
                qphi[row][m] = h16;
                qplo[row][m] = f2bf(e - bf2f(h16));
            }
        }
    __syncthreads();
    // ---- GEMM3: out-tiles. wave0 first computes denom tile (Ct rows 64..79) --
    const ushort_t* Ctb_h = Cthi + (size_t)bh * 80 * 256;
    const ushort_t* Ctb_l = Ctlo + (size_t)bh * 80 * 256;
    if (wv == 0) {
        f32x4 D4[2] = {{0.f, 0.f, 0.f, 0.f}, {0.f, 0.f, 0.f, 0.f}};
        for (int ks = 0; ks < 8; ++ks) {
            int bo = (64 + lr) * 256 + ks * 32 + 8 * lq;
            short8v b4h = *(const short8v*)(Ctb_h + bo);
            short8v b4l = *(const short8v*)(Ctb_l + bo);
            #pragma unroll
            for (int Mt = 0; Mt < 2; ++Mt) {
                short8v a3h = *(const short8v*)&qphi[Mt * 16 + lr][ks * 32 + 8 * lq];
                short8v a3l = *(const short8v*)&qplo[Mt * 16 + lr][ks * 32 + 8 * lq];
                D4[Mt] = MFMA16(a3h, b4h, D4[Mt]);
                D4[Mt] = MFMA16(a3h, b4l, D4[Mt]);
                D4[Mt] = MFMA16(a3l, b4h, D4[Mt]);
            }
        }
        if (lr == 0) {
            #pragma unroll
            for (int Mt = 0; Mt < 2; ++Mt)
                #pragma unroll
                for (int reg = 0; reg < 4; ++reg)
                    dnv[Mt * 16 + lq * 4 + reg] = 1.f / D4[Mt][reg];
        }
    }
    f32x4 D3[2] = {{0.f, 0.f, 0.f, 0.f}, {0.f, 0.f, 0.f, 0.f}};
    const int d0 = wv * 16;
    for (int ks = 0; ks < 8; ++ks) {
        int bo = (d0 + lr) * 256 + ks * 32 + 8 * lq;
        short8v b3h = *(const short8v*)(Ctb_h + bo);
        short8v b3l = *(const short8v*)(Ctb_l + bo);
        #pragma unroll
        for (int Mt = 0; Mt < 2; ++Mt) {
            short8v a3h = *(const short8v*)&qphi[Mt * 16 + lr][ks * 32 + 8 * lq];
            short8v a3l = *(const short8v*)&qplo[Mt * 16 + lr][ks * 32 + 8 * lq];
            D3[Mt] = MFMA16(a3h, b3h, D3[Mt]);
            D3[Mt] = MFMA16(a3h, b3l, D3[Mt]);
            D3[Mt] = MFMA16(a3l, b3h, D3[Mt]);
        }
    }
    __syncthreads();
    #pragma unroll
    for (int Mt = 0; Mt < 2; ++Mt)
        #pragma unroll
        for (int reg = 0; reg < 4; ++reg) {
            int row = Mt * 16 + lq * 4 + reg;
            out[((size_t)bh * NSEQ + r0 + row) * DD + d0 + lr] = D3[Mt][reg] * dnv[row];
        }
}

extern "C" void kernel_launch(void* const* d_in, const int* in_sizes, int n_in,
                              void* d_out, int out_size, void* d_ws, size_t ws_size,
                              hipStream_t stream) {
    const float* Q    = (const float*)d_in[0];
    const float* K    = (const float*)d_in[1];
    const float* V    = (const float*)d_in[2];
    const float* mask = (const float*)d_in[3];
    const float* proj = (const float*)d_in[4];
    float* out = (float*)d_out;
    char* ws = (char*)d_ws;

    float*    mx    = (float*)ws;                   // 4 B
    float*    apart = (float*)(ws + 256);           // 768 f32
    float*    ksum  = (float*)(ws + 4096);          // 48*256 f32
    float*    ctx   = (float*)(ws + 65536);         // 48*256*64 f32 -> ends 3,211,264
    ushort_t* Cthi  = (ushort_t*)(ws + 3211264);    // 48*80*256 u16
    ushort_t* Ctlo  = (ushort_t*)(ws + 5177344);
    ushort_t* Phi   = (ushort_t*)(ws + 7143424);    // 256*64 u16
    ushort_t* Plo   = (ushort_t*)(ws + 7176192);    // ends 7,208,960 (~7.2 MB)

    hipMemsetAsync(ws + 4096, 0, 3211264 - 4096, stream);  // zero ksum+ctx

    prep_kernel<<<64, 256, 0, stream>>>(proj, Phi, Plo);
    kmax_mfma<<<BH * 16, 256, 0, stream>>>(K, mask, Phi, Plo, apart);
    kmax_reduce<<<1, 256, 0, stream>>>(apart, mx);
    kctx_mfma<<<BH * 16, 256, 0, stream>>>(K, V, mask, Phi, Plo, mx, ctx, ksum);
    ctxcvt_kernel<<<BH, 256, 0, stream>>>(ctx, ksum, Cthi, Ctlo);
    qout_mfma<<<BH * 128, 256, 0, stream>>>(Q, Phi, Plo, Cthi, Ctlo, out);
}